// Round 5
// baseline (728.498 us; speedup 1.0000x reference)
//
#include <hip/hip_runtime.h>
#include <math.h>

// Problem constants (from reference)
#define DD 128
#define SS 255          // 2*D-1 shift candidates
#define HDIM 1024
#define CDIM 128
#define NPOS 4096       // B*T = 8*512
#define TEMPER 0.85f
#define ENERGY_TH 0.01f

// ---------------------------------------------------------------------------
// Init: copy residuals, zero accumulators (ws is poisoned 0xAA every call)
// ---------------------------------------------------------------------------
__global__ __launch_bounds__(256) void k_init(const float* __restrict__ x, const float* __restrict__ y,
                                              float* __restrict__ xr, float* __restrict__ yr,
                                              float* __restrict__ energy, float* __restrict__ maskp,
                                              float* __restrict__ scal) {
    int gid = blockIdx.x * 256 + threadIdx.x;
    for (int i = gid; i < NPOS * DD; i += gridDim.x * 256) { xr[i] = x[i]; yr[i] = y[i]; }
    if (gid < HDIM) { energy[gid] = 0.f; maskp[gid] = 0.f; }
    if (gid < 8)    { scal[gid] = 0.f; }
}

// ---------------------------------------------------------------------------
// K1a: wave-synchronous align. 4 positions per 256-thr block, one wave each.
// Lane l owns shifts 4l..4l+3 via float4 sliding window; all reductions are
// wave shuffles. Barriers only for LDS write->read ordering safety.
// ---------------------------------------------------------------------------
__global__ __launch_bounds__(256) void k_align(float* __restrict__ xr_g, const float* __restrict__ yr_g,
                                               float* __restrict__ V_g) {
    __shared__ __align__(16) float xsp[4][384];   // zero-padded x window
    __shared__ __align__(16) float vpad[4][384];  // zero-padded v window
    __shared__ __align__(16) float ysl[4][128];
    __shared__ float Pfl[4][128];

    const int t = threadIdx.x;
    const int w = t >> 6;         // wave 0..3
    const int l = t & 63;         // lane
    const int pos = blockIdx.x * 4 + w;

    float* xs = xsp[w];
    float* vp = vpad[w];
    float* yw = ysl[w];
    float* pf = Pfl[w];

    // zero the pad regions (covers 0..126 and 255..383)
    for (int i = l; i < 127; i += 64) { xs[i] = 0.f; vp[i] = 0.f; }
    for (int i = 255 + l; i < 384; i += 64) { xs[i] = 0.f; vp[i] = 0.f; }

    // load x,y as float2 per lane
    const float2 x2 = *(const float2*)(xr_g + pos * DD + 2 * l);
    const float2 y2 = *(const float2*)(yr_g + pos * DD + 2 * l);
    xs[127 + 2 * l] = x2.x; xs[128 + 2 * l] = x2.y;
    yw[2 * l] = y2.x; yw[2 * l + 1] = y2.y;

    // inclusive prefix sum of x^2 over 128 elems (pair per lane + wave scan)
    float a = x2.x * x2.x, b = x2.y * x2.y;
    float c = a + b;
    #pragma unroll
    for (int off = 1; off < 64; off <<= 1) {
        float n = __shfl_up(c, off);
        if (l >= off) c += n;
    }
    float excl = c - (a + b);
    pf[2 * l]     = excl + a;
    pf[2 * l + 1] = c;

    // ||y||^2 via butterfly
    float yn = y2.x * y2.x + y2.y * y2.y;
    #pragma unroll
    for (int off = 32; off > 0; off >>= 1) yn += __shfl_xor(yn, off);

    __syncthreads();   // xs/yw/pf visible

    // correlation: shifts s = 4l..4l+3, float4 sliding window over d
    float acc0 = 0.f, acc1 = 0.f, acc2 = 0.f, acc3 = 0.f;
    const float4* xs4 = (const float4*)(xs + 4 * l);
    const float4* yw4 = (const float4*)yw;
    float4 xa = xs4[0];
    #pragma unroll 4
    for (int j = 0; j < 32; ++j) {
        float4 xb = xs4[j + 1];
        float4 yv = yw4[j];
        acc0 = fmaf(xa.x, yv.x, fmaf(xa.y, yv.y, fmaf(xa.z, yv.z, fmaf(xa.w, yv.w, acc0))));
        acc1 = fmaf(xa.y, yv.x, fmaf(xa.z, yv.y, fmaf(xa.w, yv.z, fmaf(xb.x, yv.w, acc1))));
        acc2 = fmaf(xa.z, yv.x, fmaf(xa.w, yv.y, fmaf(xb.x, yv.z, fmaf(xb.y, yv.w, acc2))));
        acc3 = fmaf(xa.w, yv.x, fmaf(xb.x, yv.y, fmaf(xb.y, yv.z, fmaf(xb.z, yv.w, acc3))));
        xa = xb;
    }

    // sims + local argmax (ascending s, strict > keeps first occurrence)
    float best = -INFINITY; int bidx = 0;
    float accs[4] = {acc0, acc1, acc2, acc3};
    #pragma unroll
    for (int k = 0; k < 4; ++k) {
        int s = 4 * l + k;
        float nrm2 = pf[s < DD ? s : DD - 1] - ((s >= DD) ? pf[s - DD] : 0.f);
        nrm2 = fmaxf(nrm2, 0.f);
        float denom = sqrtf(nrm2) * sqrtf(yn);
        float sim = (denom > 0.f) ? accs[k] / fmaxf(denom, 1e-12f) : 0.f;
        if (s == SS) sim = -INFINITY;          // s=255 is out of range
        if (sim > best) { best = sim; bidx = s; }
    }
    // wave argmax (max value, min index tie-break)
    #pragma unroll
    for (int off = 32; off > 0; off >>= 1) {
        float ov = __shfl_xor(best, off);
        int   oi = __shfl_xor(bidx, off);
        if (ov > best || (ov == best && oi < bidx)) { best = ov; bidx = oi; }
    }
    const int theta = bidx;

    // attention softmax over d (2 elems per lane: d=l and d=l+64)
    const int d0 = l, d1 = l + 64;
    float ya0 = xs[theta + d0], ya1 = xs[theta + d1];
    float z0 = ya0 * yw[d0] / TEMPER;
    float z1 = ya1 * yw[d1] / TEMPER;
    float zm = fmaxf(z0, z1);
    #pragma unroll
    for (int off = 32; off > 0; off >>= 1) zm = fmaxf(zm, __shfl_xor(zm, off));
    float e0 = expf(z0 - zm), e1 = expf(z1 - zm);
    float es = e0 + e1;
    #pragma unroll
    for (int off = 32; off > 0; off >>= 1) es += __shfl_xor(es, off);
    float v0 = ya0 * (e0 / es);
    float v1 = ya1 * (e1 / es);
    vp[127 + d0] = v0;
    vp[127 + d1] = v1;
    V_g[pos * DD + d0] = v0;
    V_g[pos * DD + d1] = v1;

    __syncthreads();   // vp visible

    // reverse shift -> x_ele; update x_res
    float xe0 = vp[d0 + 2 * (DD - 1) - theta];
    float xe1 = vp[d1 + 2 * (DD - 1) - theta];
    xr_g[pos * DD + d0] = xs[127 + d0] - xe0;
    xr_g[pos * DD + d1] = xs[127 + d1] - xe1;
}

// ---------------------------------------------------------------------------
// K1b: energy[j] += sum over rows of relu(V @ W_enc)^2   (no h stored)
// block: 64 rows x 256 cols; thread: 16 rows x 4 cols register tile.
// grid (4096/64, 1024/256) = (64,4), 256 thr. We-traffic = 128 MB L2-resident
// per call (< FMA floor); all global loads float4-coalesced.
// ---------------------------------------------------------------------------
#define MT 64
__global__ __launch_bounds__(256) void k_energy(const float* __restrict__ V_g, const float* __restrict__ We,
                                                float* __restrict__ energy) {
    __shared__ __align__(16) float Vl[MT][DD];   // 32 KB
    const int t  = threadIdx.x;
    const int tx = t & 63;          // col group: 4 cols each
    const int ty = t >> 6;          // row group: 16 rows each (0..3)
    const int m0 = blockIdx.x * MT;
    const int n0 = blockIdx.y * 256;
    const int j  = n0 + tx * 4;
    const int r0 = ty * 16;

    const float4* v4 = (const float4*)(V_g + m0 * DD);
    float4* vl4 = (float4*)(&Vl[0][0]);
    #pragma unroll
    for (int i = 0; i < 8; ++i) vl4[t + 256 * i] = v4[t + 256 * i];
    __syncthreads();

    float acc[16][4];
    #pragma unroll
    for (int r = 0; r < 16; ++r)
        #pragma unroll
        for (int cc = 0; cc < 4; ++cc) acc[r][cc] = 0.f;

    for (int d0 = 0; d0 < DD; d0 += 4) {
        float wreg[4][4];
        #pragma unroll
        for (int dd = 0; dd < 4; ++dd) {
            float4 wa = *(const float4*)(We + (d0 + dd) * HDIM + j);
            wreg[dd][0] = wa.x; wreg[dd][1] = wa.y; wreg[dd][2] = wa.z; wreg[dd][3] = wa.w;
        }
        #pragma unroll
        for (int r = 0; r < 16; ++r) {
            float4 v = *(const float4*)(&Vl[r0 + r][d0]);
            float vv[4] = {v.x, v.y, v.z, v.w};
            #pragma unroll
            for (int dd = 0; dd < 4; ++dd)
                #pragma unroll
                for (int cc = 0; cc < 4; ++cc)
                    acc[r][cc] = fmaf(vv[dd], wreg[dd][cc], acc[r][cc]);
        }
    }

    // per-col relu^2 partials -> LDS (alias Vl) -> one atomic per col
    __syncthreads();            // done reading Vl
    float* Ps = &Vl[0][0];      // [4][256]
    #pragma unroll
    for (int cc = 0; cc < 4; ++cc) {
        float e = 0.f;
        #pragma unroll
        for (int r = 0; r < 16; ++r) { float h = fmaxf(acc[r][cc], 0.f); e = fmaf(h, h, e); }
        Ps[ty * 256 + tx * 4 + cc] = e;
    }
    __syncthreads();
    float esum = 0.f;
    #pragma unroll
    for (int q = 0; q < 4; ++q) esum += Ps[q * 256 + t];
    atomicAdd(&energy[n0 + t], esum);
}

// ---------------------------------------------------------------------------
// K2: single block, 1024 thr — top-128 selection (bitonic sort, index
// tie-break = jax.lax.top_k), loss_h, compacted weight gather, plus finalize
// of PREVIOUS iteration's loss_local. Compaction order is irrelevant (set
// semantics; all downstream sums permutation-invariant) -> sel_l[t]=si[t].
// ---------------------------------------------------------------------------
__global__ __launch_bounds__(1024) void k_select(float* __restrict__ energy, float* __restrict__ maskp,
                                                 float* __restrict__ scal,
                                                 const float* __restrict__ We, const float* __restrict__ Wd,
                                                 float* __restrict__ Wes, float* __restrict__ Wds, int iter) {
    __shared__ float sv[HDIM];
    __shared__ int   si[HDIM];
    __shared__ int   mk[HDIM];
    __shared__ float red[HDIM];
    __shared__ int   sel_l[CDIM];

    const int t = threadIdx.x;
    if (t == 0) {
        if (iter > 0) scal[3] += scal[0] / fmaxf(scal[1], 1.f) + scal[2];
        scal[0] = 0.f; scal[1] = 0.f;
    }
    float e = energy[t] * (1.0f / (float)NPOS);   // mean over (B,T)
    sv[t] = (maskp[t] > 0.f) ? -INFINITY : e;
    si[t] = t;
    __syncthreads();

    // bitonic sort, "before" = (larger value) or (equal value, smaller index)
    for (int k = 2; k <= HDIM; k <<= 1) {
        for (int j = k >> 1; j > 0; j >>= 1) {
            int ixj = t ^ j;
            if (ixj > t) {
                bool up = ((t & k) == 0);
                float va = sv[t], vb = sv[ixj];
                int ia = si[t], ib = si[ixj];
                bool inorder = (va > vb) || (va == vb && ia < ib);
                if (up != inorder) { sv[t] = vb; si[t] = ib; sv[ixj] = va; si[ixj] = ia; }
            }
            __syncthreads();
        }
    }

    mk[t] = 0;
    __syncthreads();
    if (t < CDIM) { mk[si[t]] = 1; sel_l[t] = si[t]; }
    __syncthreads();
    const int mym = mk[t];

    // loss_h = (sum_all - sum_selected)/HDIM
    red[t] = e;
    __syncthreads();
    for (int off = 512; off > 0; off >>= 1) { if (t < off) red[t] += red[t + off]; __syncthreads(); }
    const float sum_all = red[0];
    __syncthreads();
    red[t] = mym ? e : 0.f;
    __syncthreads();
    for (int off = 512; off > 0; off >>= 1) { if (t < off) red[t] += red[t + off]; __syncthreads(); }
    const float sum_sel = red[0];
    if (t == 0) scal[2] = (sum_all - sum_sel) / (float)HDIM;

    maskp[t] = maskp[t] + (float)mym;
    energy[t] = 0.f;     // ready for next iteration
    __syncthreads();

    // gather compacted weights: Wes[d][k] = We[d][sel[k]], Wds[k][d] = Wd[sel[k]][d]
    for (int i = t; i < DD * CDIM; i += HDIM) {
        int d = i >> 7, kk = i & 127;
        Wes[i] = We[d * HDIM + sel_l[kk]];
    }
    for (int i = t; i < CDIM * DD; i += HDIM) {
        int kk = i >> 7, d = i & 127;
        Wds[i] = Wd[sel_l[kk] * DD + d];
    }
}

// ---------------------------------------------------------------------------
// K3: y_ele = relu(V@Wes)@Wds (h_sel in LDS only), masked MSE sums, y_res -=
// grid 128 blocks x 256 thr, 32 rows/block
// ---------------------------------------------------------------------------
#define RT 32
__global__ __launch_bounds__(256) void k_decode(const float* __restrict__ V_g, const float* __restrict__ Wes,
                                                const float* __restrict__ Wds, float* __restrict__ yr_g,
                                                const float* __restrict__ y_orig, float* __restrict__ scal) {
    __shared__ __align__(16) float Vl[RT][DD];
    __shared__ __align__(16) float Hs[RT][CDIM];
    __shared__ float ren[RT];
    __shared__ float redf[256];

    const int t = threadIdx.x;
    const int r0 = blockIdx.x * RT;

    const float4* v4 = (const float4*)(V_g + r0 * DD);
    float4* vl4 = (float4*)(&Vl[0][0]);
    #pragma unroll
    for (int i = 0; i < 4; ++i) vl4[t + 256 * i] = v4[t + 256 * i];

    // row energies of y_res (mean over d), 8 threads/row
    {
        int r = t >> 3, lane8 = t & 7;
        float s = 0.f;
        const float* yp = yr_g + (r0 + r) * DD + lane8 * 16;
        #pragma unroll
        for (int c = 0; c < 16; ++c) { float v = yp[c]; s = fmaf(v, v, s); }
        s += __shfl_xor(s, 1); s += __shfl_xor(s, 2); s += __shfl_xor(s, 4);
        if (lane8 == 0) ren[r] = s * (1.f / (float)DD);
    }
    __syncthreads();

    const int half = t >> 7;     // 0..1 -> 16 rows each
    const int k = t & 127;

    // phase 1: Hs = relu(V @ Wes)
    {
        float acc[16];
        #pragma unroll
        for (int r = 0; r < 16; ++r) acc[r] = 0.f;
        for (int d0 = 0; d0 < DD; d0 += 4) {
            float w0 = Wes[(d0 + 0) * CDIM + k];
            float w1 = Wes[(d0 + 1) * CDIM + k];
            float w2 = Wes[(d0 + 2) * CDIM + k];
            float w3 = Wes[(d0 + 3) * CDIM + k];
            #pragma unroll
            for (int r = 0; r < 16; ++r) {
                float4 v = *(const float4*)(&Vl[half * 16 + r][d0]);
                acc[r] = fmaf(v.x, w0, fmaf(v.y, w1, fmaf(v.z, w2, fmaf(v.w, w3, acc[r]))));
            }
        }
        #pragma unroll
        for (int r = 0; r < 16; ++r) Hs[half * 16 + r][k] = fmaxf(acc[r], 0.f);
    }
    __syncthreads();

    // phase 2: y_ele = Hs @ Wds; loss sums; y_res update
    {
        float acc[16];
        #pragma unroll
        for (int r = 0; r < 16; ++r) acc[r] = 0.f;
        for (int k0 = 0; k0 < CDIM; k0 += 4) {
            float w0 = Wds[(k0 + 0) * DD + k];
            float w1 = Wds[(k0 + 1) * DD + k];
            float w2 = Wds[(k0 + 2) * DD + k];
            float w3 = Wds[(k0 + 3) * DD + k];
            #pragma unroll
            for (int r = 0; r < 16; ++r) {
                float4 h = *(const float4*)(&Hs[half * 16 + r][k0]);
                acc[r] = fmaf(h.x, w0, fmaf(h.y, w1, fmaf(h.z, w2, fmaf(h.w, w3, acc[r]))));
            }
        }
        float sd = 0.f, svld = 0.f;
        #pragma unroll
        for (int r = 0; r < 16; ++r) {
            int row = r0 + half * 16 + r;
            float tgt = yr_g[row * DD + k];
            float yo  = y_orig[row * DD + k];
            bool valid = (yo != 0.f) && (ren[half * 16 + r] > ENERGY_TH);
            float diff = acc[r] - tgt;
            if (valid) { sd = fmaf(diff, diff, sd); svld += 1.f; }
            yr_g[row * DD + k] = tgt - acc[r];
        }
        redf[t] = sd;
        __syncthreads();
        for (int off = 128; off > 0; off >>= 1) { if (t < off) redf[t] += redf[t + off]; __syncthreads(); }
        if (t == 0) atomicAdd(&scal[0], redf[0]);
        __syncthreads();
        redf[t] = svld;
        __syncthreads();
        for (int off = 128; off > 0; off >>= 1) { if (t < off) redf[t] += redf[t + off]; __syncthreads(); }
        if (t == 0) atomicAdd(&scal[1], redf[0]);
    }
}

// ---------------------------------------------------------------------------
// final: close out iteration 8, write mean of 8 losses
// ---------------------------------------------------------------------------
__global__ void k_final(const float* __restrict__ scal, float* __restrict__ out) {
    float total = scal[3] + scal[0] / fmaxf(scal[1], 1.f) + scal[2];
    out[0] = total * (1.f / 8.f);
}

extern "C" void kernel_launch(void* const* d_in, const int* in_sizes, int n_in,
                              void* d_out, int out_size, void* d_ws, size_t ws_size,
                              hipStream_t stream) {
    const float* x  = (const float*)d_in[0];
    const float* y  = (const float*)d_in[1];
    const float* We = (const float*)d_in[2];
    const float* Wd = (const float*)d_in[3];

    float* ws     = (float*)d_ws;
    float* xr     = ws;                 // 524288
    float* yr     = ws + 524288;        // 524288
    float* V      = ws + 1048576;       // 524288
    float* Wes    = ws + 1572864;       // 16384
    float* Wds    = ws + 1589248;       // 16384
    float* energy = ws + 1605632;       // 1024
    float* maskp  = ws + 1606656;       // 1024
    float* scal   = ws + 1607808;       // 8
    float* out    = (float*)d_out;

    k_init<<<2048, 256, 0, stream>>>(x, y, xr, yr, energy, maskp, scal);
    for (int it = 0; it < 8; ++it) {
        k_align<<<NPOS / 4, 256, 0, stream>>>(xr, yr, V);
        k_energy<<<dim3(NPOS / MT, HDIM / 256), 256, 0, stream>>>(V, We, energy);
        k_select<<<1, 1024, 0, stream>>>(energy, maskp, scal, We, Wd, Wes, Wds, it);
        k_decode<<<NPOS / RT, 256, 0, stream>>>(V, Wes, Wds, yr, y, scal);
    }
    k_final<<<1, 1, 0, stream>>>(scal, out);
}